// Round 10
// baseline (616.507 us; speedup 1.0000x reference)
//
#include <hip/hip_runtime.h>
#include <hip/hip_bf16.h>
#include <math.h>

#define DIMM   1024
#define NHEADS 16
#define DHEAD  64
#define BATCH  2
#define SEQ    2048
#define NKEYS  (SEQ + 1)      // 2049 (null + seq)
#define NKROWS 2176           // padded K rows (128-key tiles: up to 2175)
#define NKP    2176           // padded key count for V^T inner dim
#define PBROWS (2 * SEQ - 1)  // 4095
#define ROWS   (BATCH * SEQ)  // 4096

using bf16x8 = __attribute__((ext_vector_type(8))) short;
using bf16x4 = __attribute__((ext_vector_type(4))) short;
using f32x4  = __attribute__((ext_vector_type(4))) float;
typedef unsigned int u32;
typedef unsigned short u16;

__device__ __forceinline__ u16 f2bf(float f) {
  __hip_bfloat16 h = __float2bfloat16(f);
  return __builtin_bit_cast(u16, h);
}
__device__ __forceinline__ float bf2f(u16 u) {
  u32 x = ((u32)u) << 16;
  return __builtin_bit_cast(float, x);
}
__device__ __forceinline__ void gl_lds16(const void* g, void* l) {
  __builtin_amdgcn_global_load_lds(
      (const __attribute__((address_space(1))) u32*)g,
      (__attribute__((address_space(3))) u32*)l, 16, 0, 0);
}
// K=16 bf16 MFMA (PV step): D = A*B + C, in-place accumulate.
__device__ __forceinline__ f32x4 mfma16(bf16x4 a, bf16x4 b, f32x4 c) {
  asm("v_mfma_f32_16x16x16_bf16 %0, %1, %2, %0" : "+v"(c) : "v"(a), "v"(b));
  return c;
}

// ---------------------------------------------------------------------------
// LayerNorm over last dim (=1024).  obf16: output bf16.  posrow: input is
// w0[c]*(row-(SEQ-1)) + addb[c]  (fused dynamic-pos-bias first layer).
// ---------------------------------------------------------------------------
__global__ __launch_bounds__(256) void ln_kernel(
    const float* __restrict__ in, const float* __restrict__ addb,
    const float* __restrict__ g, const float* __restrict__ bvec,
    void* __restrict__ outv, int silu, int obf16, int posrow) {
  int row = blockIdx.x;
  int t = threadIdx.x;
  float4 x;
  if (posrow) {
    float p = (float)(row - (SEQ - 1));
    float4 wv = ((const float4*)in)[t];
    float4 a = ((const float4*)addb)[t];
    x.x = p * wv.x + a.x; x.y = p * wv.y + a.y;
    x.z = p * wv.z + a.z; x.w = p * wv.w + a.w;
  } else {
    x = ((const float4*)(in + (size_t)row * DIMM))[t];
    if (addb) {
      float4 a = ((const float4*)addb)[t];
      x.x += a.x; x.y += a.y; x.z += a.z; x.w += a.w;
    }
  }
  float s  = x.x + x.y + x.z + x.w;
  float ss = x.x * x.x + x.y * x.y + x.z * x.z + x.w * x.w;
#pragma unroll
  for (int off = 32; off > 0; off >>= 1) {
    s  += __shfl_down(s, off);
    ss += __shfl_down(ss, off);
  }
  __shared__ float rs[4], rss[4];
  int wv_ = t >> 6, lane = t & 63;
  if (lane == 0) { rs[wv_] = s; rss[wv_] = ss; }
  __syncthreads();
  float S  = rs[0] + rs[1] + rs[2] + rs[3];
  float SS = rss[0] + rss[1] + rss[2] + rss[3];
  float mu  = S * (1.0f / DIMM);
  float var = SS * (1.0f / DIMM) - mu * mu;
  float inv = rsqrtf(var + 1e-5f);
  float4 gv = ((const float4*)g)[t];
  float4 bv = ((const float4*)bvec)[t];
  float4 o;
  o.x = (x.x - mu) * inv * gv.x + bv.x;
  o.y = (x.y - mu) * inv * gv.y + bv.y;
  o.z = (x.z - mu) * inv * gv.z + bv.z;
  o.w = (x.w - mu) * inv * gv.w + bv.w;
  if (silu) {
    o.x = o.x / (1.f + expf(-o.x));
    o.y = o.y / (1.f + expf(-o.y));
    o.z = o.z / (1.f + expf(-o.z));
    o.w = o.w / (1.f + expf(-o.w));
  }
  if (obf16) {
    ushort4 ob;
    ob.x = f2bf(o.x); ob.y = f2bf(o.y); ob.z = f2bf(o.z); ob.w = f2bf(o.w);
    ((ushort4*)((u16*)outv + (size_t)row * DIMM))[t] = ob;
  } else {
    ((float4*)((float*)outv + (size_t)row * DIMM))[t] = o;
  }
}

// ---------------------------------------------------------------------------
// Weight convert+transpose: W f32 [K=1024][N] -> WT bf16 [rowOff+N][1024]
// ---------------------------------------------------------------------------
__global__ __launch_bounds__(256) void conv_wT(
    const float* __restrict__ W, u16* __restrict__ WT, int N, int rowOff) {
  __shared__ float tile[32][33];
  const int n0 = blockIdx.x * 32, k0 = blockIdx.y * 32;
  const int tc = threadIdx.x & 31, tr = threadIdx.x >> 5;  // tr 0..7
#pragma unroll
  for (int i = 0; i < 4; ++i)
    tile[tr + i * 8][tc] = W[(size_t)(k0 + tr + i * 8) * N + n0 + tc];
  __syncthreads();
#pragma unroll
  for (int i = 0; i < 4; ++i) {
    int r = tr + i * 8;
    WT[(size_t)(rowOff + n0 + r) * 1024 + k0 + tc] = f2bf(tile[tc][r]);
  }
}

// ---------------------------------------------------------------------------
// bf16 MFMA GEMM, split-K=2 via blockIdx.z, atomicAdd epilogue (C must be
// zeroed first).  2x blocks/CU vs the 1/CU m97 grid at N<=1152.
// ---------------------------------------------------------------------------
__global__ __launch_bounds__(256) void gemm_bf16(
    const u16* __restrict__ A, const u16* __restrict__ BT,
    float* __restrict__ C, int M, int N, int K) {
  __shared__ u16 As[128 * 32];
  __shared__ u16 Bs[128 * 32];
  const int w = threadIdx.x >> 6, lane = threadIdx.x & 63;
  const int lo = lane & 15, hi = lane >> 4;
  const int wr = w >> 1, wc = w & 1;
  const int row0 = blockIdx.y * 128, col0 = blockIdx.x * 128;
  const int kz0 = blockIdx.z * (K >> 1), kz1 = kz0 + (K >> 1);
  const int srow = lane >> 2;
  const int scol = (lane & 3) * 8;
  f32x4 acc[4][4];
#pragma unroll
  for (int m = 0; m < 4; ++m)
#pragma unroll
    for (int n = 0; n < 4; ++n) acc[m][n] = f32x4{0.f, 0.f, 0.f, 0.f};
  for (int k0 = kz0; k0 < kz1; k0 += 32) {
#pragma unroll
    for (int c = 0; c < 2; ++c) {
      const int base = 32 * w + c * 16;
      gl_lds16(A + (size_t)(row0 + base + srow) * K + k0 + scol,
               &As[base * 32]);
      gl_lds16(BT + (size_t)(col0 + base + srow) * K + k0 + scol,
               &Bs[base * 32]);
    }
    __syncthreads();
    bf16x8 af[4], bg[4];
#pragma unroll
    for (int m = 0; m < 4; ++m)
      af[m] = *(const bf16x8*)&As[(wr * 64 + m * 16 + lo) * 32 + hi * 8];
#pragma unroll
    for (int n = 0; n < 4; ++n)
      bg[n] = *(const bf16x8*)&Bs[(wc * 64 + n * 16 + lo) * 32 + hi * 8];
#pragma unroll
    for (int m = 0; m < 4; ++m)
#pragma unroll
      for (int n = 0; n < 4; ++n)
        acc[m][n] = __builtin_amdgcn_mfma_f32_16x16x32_bf16(af[m], bg[n],
                                                            acc[m][n], 0, 0, 0);
    __syncthreads();
  }
#pragma unroll
  for (int m = 0; m < 4; ++m)
#pragma unroll
    for (int r = 0; r < 4; ++r) {
      const int row = row0 + wr * 64 + m * 16 + hi * 4 + r;
      if (row < M) {
#pragma unroll
        for (int n = 0; n < 4; ++n)
          atomicAdd(&C[(size_t)row * N + col0 + wc * 64 + n * 16 + lo],
                    acc[m][n][r]);
      }
    }
}

// ---------------------------------------------------------------------------
// q relayout from tmpQKV (stride 1152, cols 0..1023) -> bf16 [b][h][i][d] /8
// ---------------------------------------------------------------------------
__global__ __launch_bounds__(256) void relayout_q(
    const float* __restrict__ tmp, u16* __restrict__ qb) {
  size_t e = (size_t)blockIdx.x * 256 + threadIdx.x;
  int m = (int)(e >> 8), c4 = (int)(e & 255);
  int b = m >> 11, i = m & 2047;
  int h = c4 >> 4, d4 = c4 & 15;
  float4 v = ((const float4*)(tmp + (size_t)m * 1152))[c4];
  const float sc = 0.125f;
  ushort4 o;
  o.x = f2bf(v.x * sc); o.y = f2bf(v.y * sc);
  o.z = f2bf(v.z * sc); o.w = f2bf(v.w * sc);
  ((ushort4*)qb)[((size_t)(b * NHEADS + h) * SEQ + i) * 16 + d4] = o;
}

// kv relayout from tmpQKV cols 1024..1151 -> k bf16 [b][j][d], v^T [b][d][j]
__global__ __launch_bounds__(256) void relayout_kv(
    const float* __restrict__ tmp, u16* __restrict__ kb, u16* __restrict__ vbT) {
  size_t e = (size_t)blockIdx.x * 256 + threadIdx.x;
  int m = (int)(e >> 5), c4 = (int)(e & 31);
  int b = m >> 11, i = m & 2047;
  float4 v = ((const float4*)(tmp + (size_t)m * 1152 + 1024))[c4];
  if (c4 < 16) {
    ushort4 o;
    o.x = f2bf(v.x); o.y = f2bf(v.y); o.z = f2bf(v.z); o.w = f2bf(v.w);
    ((ushort4*)kb)[((size_t)b * NKROWS + (i + 1)) * 16 + c4] = o;
  } else {
    int d = (c4 - 16) * 4;
    size_t base = (size_t)b * DHEAD * NKP + (size_t)d * NKP + (i + 1);
    vbT[base]           = f2bf(v.x);
    vbT[base + NKP]     = f2bf(v.y);
    vbT[base + 2 * NKP] = f2bf(v.z);
    vbT[base + 3 * NKP] = f2bf(v.w);
  }
}

__global__ void fill_null(const float* __restrict__ null_kv,
                          u16* __restrict__ kb, u16* __restrict__ vbT) {
  int b = blockIdx.x, d = threadIdx.x;
  kb[(size_t)b * NKROWS * DHEAD + d] = f2bf(null_kv[d]);
  vbT[(size_t)b * DHEAD * NKP + (size_t)d * NKP] = f2bf(null_kv[DHEAD + d]);
}

// h2: bias_tabT[h][r] = h1[r][:] . w2[:][h] + b2[h]   (transposed table)
__global__ __launch_bounds__(256) void h2_kernel(
    const u16* __restrict__ h1, const float* __restrict__ w2,
    const float* __restrict__ b2, float* __restrict__ bias_tabT) {
  int r = blockIdx.x, t = threadIdx.x;
  int col = t & 15, seg = t >> 4;
  const u16* hr = h1 + (size_t)r * DIMM + seg * 64;
  const float* w2s = w2 + (size_t)seg * 64 * NHEADS + col;
  float acc = 0.f;
#pragma unroll
  for (int c = 0; c < 8; ++c) {
    bf16x8 hv = *(const bf16x8*)(hr + c * 8);
#pragma unroll
    for (int j = 0; j < 8; ++j)
      acc += bf2f((u16)hv[j]) * w2s[(size_t)(c * 8 + j) * NHEADS];
  }
  __shared__ float p[16][16];
  p[seg][col] = acc;
  __syncthreads();
  if (t < 16) {
    float s = 0.f;
#pragma unroll
    for (int q = 0; q < 16; q++) s += p[q][t];
    bias_tabT[(size_t)t * 4096 + r] = s + b2[t];
  }
}

// ---------------------------------------------------------------------------
// Flash attention v7: 128-key tiles (halves per-tile fixed stalls: barrier,
// bias stage, max reduce, defer branch, VMEM drain).  2 waves x 32 q-rows,
// swapped QK^T, K=16 register-direct PV (O^T), LDS-staged bias, defer-max.
// Direct bf16 out (no split-K: R9 showed extra waves don't absorb the stall).
// ---------------------------------------------------------------------------
__global__ __launch_bounds__(128, 2) void flash_attn(
    const u16* __restrict__ qb, const u16* __restrict__ kb,
    const u16* __restrict__ vbT, const float* __restrict__ bias_tabT,
    const float* __restrict__ null_bias, u16* __restrict__ outb) {
  const int qt = gridDim.x - 1 - blockIdx.x;  // heavy blocks first
  const int h = blockIdx.y, b = blockIdx.z;
  const int tid = threadIdx.x;
  const int w = tid >> 6, lane = tid & 63;
  const int lo = lane & 15, hi = lane >> 4;
  const int q0 = qt * 64;
  const int rq0 = q0 + w * 32 + lo;  // f=0 q-row
  const int rq1 = rq0 + 16;          // f=1 q-row

  __shared__ float bias_lds[2][192];

  const size_t qbase = (size_t)(b * NHEADS + h) * SEQ;
  const u16* qrow0 = qb + (qbase + rq0) * DHEAD;
  const u16* qrow1 = qb + (qbase + rq1) * DHEAD;
  bf16x8 qa00 = *(const bf16x8*)(qrow0 + hi * 8);
  bf16x8 qa01 = *(const bf16x8*)(qrow0 + 32 + hi * 8);
  bf16x8 qa10 = *(const bf16x8*)(qrow1 + hi * 8);
  bf16x8 qa11 = *(const bf16x8*)(qrow1 + 32 + hi * 8);

  const u16* Kb = kb + (size_t)b * NKROWS * DHEAD;
  const u16* Vb = vbT + (size_t)b * DHEAD * NKP;
  const float* bt = bias_tabT + (size_t)h * 4096;
  const float nb = null_bias[h];

  f32x4 o[2][4];  // O^T[d = dc*16+hi*4+r][q = lane's row], per frag
#pragma unroll
  for (int f = 0; f < 2; ++f)
#pragma unroll
    for (int dc = 0; dc < 4; ++dc) o[f][dc] = f32x4{0.f, 0.f, 0.f, 0.f};
  float m_l[2] = {-3.0e38f, -3.0e38f};
  float l_l[2] = {0.f, 0.f};

  const int nkt = (qt + 3) >> 1;  // 128-key tiles covering keys 0..q0+64
  for (int kt = 0; kt < nkt; ++kt) {
    const int j0 = kt * 128;
    // ---- stage bias window (191 floats, coalesced, double-buffered) ----
    {
      const int base = q0 - j0 - 127 + SEQ;
      float* blw = bias_lds[kt & 1];
      blw[tid] = bt[base + tid];
      if (tid < 63) blw[128 + tid] = bt[base + 128 + tid];
    }
    __syncthreads();
    // ---- K frags: batch-load all 16 b128 (pipelined), then 32 QK MFMA ----
    bf16x8 kfa[8], kfb[8];
#pragma unroll
    for (int nf = 0; nf < 8; ++nf) {
      const u16* krow = Kb + (size_t)(j0 + nf * 16 + lo) * DHEAD;
      kfa[nf] = *(const bf16x8*)(krow + hi * 8);
      kfb[nf] = *(const bf16x8*)(krow + 32 + hi * 8);
    }
    f32x4 s[2][8];
    __builtin_amdgcn_s_setprio(1);
#pragma unroll
    for (int nf = 0; nf < 8; ++nf) {
      f32x4 a0 = f32x4{0.f, 0.f, 0.f, 0.f};
      f32x4 a1 = f32x4{0.f, 0.f, 0.f, 0.f};
      a0 = __builtin_amdgcn_mfma_f32_16x16x32_bf16(kfa[nf], qa00, a0, 0, 0, 0);
      a0 = __builtin_amdgcn_mfma_f32_16x16x32_bf16(kfb[nf], qa01, a0, 0, 0, 0);
      a1 = __builtin_amdgcn_mfma_f32_16x16x32_bf16(kfa[nf], qa10, a1, 0, 0, 0);
      a1 = __builtin_amdgcn_mfma_f32_16x16x32_bf16(kfb[nf], qa11, a1, 0, 0, 0);
      s[0][nf] = a0;
      s[1][nf] = a1;
    }
    __builtin_amdgcn_s_setprio(0);
    // ---- V^T frags (A of PV, K=16): row=lo->d, k=hi*4+j -> key ----
    bf16x4 vf[4][8];
#pragma unroll
    for (int dc = 0; dc < 4; ++dc) {
      const u16* vrow = Vb + (size_t)(dc * 16 + lo) * NKP + j0 + hi * 4;
#pragma unroll
      for (int kc = 0; kc < 8; ++kc)
        vf[dc][kc] = *(const bf16x4*)(vrow + kc * 16);
    }
    // ---- bias (from LDS) + causal mask + row max ----
    const float* bl = bias_lds[kt & 1];
    float tm[2] = {-3.0e38f, -3.0e38f};
#pragma unroll
    for (int f = 0; f < 2; ++f) {
      const int rq = (f == 0) ? rq0 : rq1;
      const int qoff = w * 32 + f * 16 + lo + 127;
#pragma unroll
      for (int nf = 0; nf < 8; ++nf)
#pragma unroll
        for (int r = 0; r < 4; ++r) {
          const int krel = nf * 16 + hi * 4 + r;
          const int key = j0 + krel;
          float bias = bl[qoff - krel];
          if (key == 0) bias = nb;
          float v = (key <= rq + 1) ? (s[f][nf][r] + bias) : -3.0e38f;
          s[f][nf][r] = v;
          tm[f] = fmaxf(tm[f], v);
        }
      tm[f] = fmaxf(tm[f], __shfl_xor(tm[f], 16));
      tm[f] = fmaxf(tm[f], __shfl_xor(tm[f], 32));
    }
    // ---- defer-max rescale (lane-local o) ----
    if (__any((tm[0] > m_l[0] + 8.0f) || (tm[1] > m_l[1] + 8.0f))) {
#pragma unroll
      for (int f = 0; f < 2; ++f) {
        float mn = fmaxf(m_l[f], tm[f]);
        float sco = __expf(m_l[f] - mn);
        m_l[f] = mn;
        l_l[f] *= sco;
#pragma unroll
        for (int dc = 0; dc < 4; ++dc)
#pragma unroll
          for (int r = 0; r < 4; ++r) o[f][dc][r] *= sco;
      }
    }
    // ---- exp + per-lane partial sum + pack P as K=16 B-frags ----
    bf16x4 pbf[2][8];
#pragma unroll
    for (int f = 0; f < 2; ++f)
#pragma unroll
      for (int nf = 0; nf < 8; ++nf) {
        float p0 = __expf(s[f][nf][0] - m_l[f]);
        float p1 = __expf(s[f][nf][1] - m_l[f]);
        float p2 = __expf(s[f][nf][2] - m_l[f]);
        float p3 = __expf(s[f][nf][3] - m_l[f]);
        l_l[f] += (p0 + p1) + (p2 + p3);
        pbf[f][nf][0] = (short)f2bf(p0);
        pbf[f][nf][1] = (short)f2bf(p1);
        pbf[f][nf][2] = (short)f2bf(p2);
        pbf[f][nf][3] = (short)f2bf(p3);
      }
    // ---- O^T += V^T @ P^T (64x K=16 MFMA, register-direct) ----
    __builtin_amdgcn_s_setprio(1);
#pragma unroll
    for (int f = 0; f < 2; ++f)
#pragma unroll
      for (int dc = 0; dc < 4; ++dc)
#pragma unroll
        for (int kc = 0; kc < 8; ++kc)
          o[f][dc] = mfma16(vf[dc][kc], pbf[f][kc], o[f][dc]);
    __builtin_amdgcn_s_setprio(0);
  }
  asm volatile("s_nop 7\ns_nop 7" :::);  // asm-MFMA -> VALU hazard guard
  // ---- final l reduce + lane-local normalize + stores ----
#pragma unroll
  for (int f = 0; f < 2; ++f) {
    float lf = l_l[f];
    lf += __shfl_xor(lf, 16);
    lf += __shfl_xor(lf, 32);
    float linv = 1.0f / lf;
    const int rq = (f == 0) ? rq0 : rq1;
    u16* orow = outb + (size_t)(b * SEQ + rq) * DIMM + h * DHEAD + hi * 4;
#pragma unroll
    for (int dc = 0; dc < 4; ++dc) {
      ushort4 st;
      st.x = f2bf(o[f][dc][0] * linv);
      st.y = f2bf(o[f][dc][1] * linv);
      st.z = f2bf(o[f][dc][2] * linv);
      st.w = f2bf(o[f][dc][3] * linv);
      *(ushort4*)(orow + dc * 16) = st;
    }
  }
}

// ---------------------------------------------------------------------------
extern "C" void kernel_launch(void* const* d_in, const int* in_sizes, int n_in,
                              void* d_out, int out_size, void* d_ws,
                              size_t ws_size, hipStream_t stream) {
  const float* x         = (const float*)d_in[0];
  const float* ln_g      = (const float*)d_in[1];
  const float* ln_b      = (const float*)d_in[2];
  const float* Wq        = (const float*)d_in[3];
  const float* Wkv       = (const float*)d_in[4];
  const float* null_kv   = (const float*)d_in[5];
  const float* null_bias = (const float*)d_in[6];
  const float* pb_w0     = (const float*)d_in[7];
  const float* pb_b0     = (const float*)d_in[8];
  const float* pb_ln0_g  = (const float*)d_in[9];
  const float* pb_ln0_b  = (const float*)d_in[10];
  const float* pb_w1     = (const float*)d_in[11];
  const float* pb_b1     = (const float*)d_in[12];
  const float* pb_ln1_g  = (const float*)d_in[13];
  const float* pb_ln1_b  = (const float*)d_in[14];
  const float* pb_w2     = (const float*)d_in[15];
  const float* pb_b2     = (const float*)d_in[16];
  const float* Wo        = (const float*)d_in[17];
  const float* out_ln_g  = (const float*)d_in[18];
  const float* out_ln_b  = (const float*)d_in[19];
  float* out = (float*)d_out;

  char* ws = (char*)d_ws;
  float* regA      = (float*)(ws);                      // f32 4096x1152
  u16*   h1_bf     = (u16*)(ws + 18874368);             // bf16 4095x1024
  u16*   regC      = (u16*)(ws + 35651584);             // bf16 4096x1024
  u16*   qb        = (u16*)(ws + 44040192);             // bf16 q
  u16*   kb        = (u16*)(ws + 52428800);             // bf16 K padded (557056B)
  u16*   vbT       = (u16*)(ws + 52985856);             // bf16 V^T padded
  u16*   wqkvT     = (u16*)(ws + 53542912);             // 1152x1024 bf16
  u16*   w1T       = (u16*)(ws + 55902208);             // 1024x1024 bf16
  u16*   woT       = (u16*)(ws + 57999360);             // 1024x1024 bf16
  float* bias_tabT = (float*)(ws + 60096512);           // f32 [16][4096]

  hipMemsetAsync((void*)kb, 0, 1114112, stream);        // K + V^T padding

  conv_wT<<<dim3(32, 32), 256, 0, stream>>>(Wq, wqkvT, 1024, 0);
  conv_wT<<<dim3(4, 32), 256, 0, stream>>>(Wkv, wqkvT, 128, 1024);
  conv_wT<<<dim3(32, 32), 256, 0, stream>>>(pb_w1, w1T, 1024, 0);
  conv_wT<<<dim3(32, 32), 256, 0, stream>>>(Wo, woT, 1024, 0);

  // 1. xn = LN(x) -> bf16
  ln_kernel<<<ROWS, 256, 0, stream>>>(x, nullptr, ln_g, ln_b, regC, 0, 1, 0);
  // 2. fused q|kv GEMM (split-K=2, atomic into zeroed C)
  hipMemsetAsync((void*)regA, 0, 18874368, stream);
  gemm_bf16<<<dim3(9, 32, 2), 256, 0, stream>>>(regC, wqkvT, regA, ROWS, 1152,
                                                1024);
  relayout_q<<<4096, 256, 0, stream>>>(regA, qb);
  relayout_kv<<<512, 256, 0, stream>>>(regA, kb, vbT);
  fill_null<<<2, 64, 0, stream>>>(null_kv, kb, vbT);
  // 3. pos-bias MLP (first layer fused into LN)
  ln_kernel<<<PBROWS, 256, 0, stream>>>(pb_w0, pb_b0, pb_ln0_g, pb_ln0_b, regC,
                                        1, 1, 1);
  hipMemsetAsync((void*)regA, 0, 16773120, stream);
  gemm_bf16<<<dim3(8, 32, 2), 256, 0, stream>>>(regC, w1T, regA, PBROWS, 1024,
                                                1024);
  ln_kernel<<<PBROWS, 256, 0, stream>>>(regA, pb_b1, pb_ln1_g, pb_ln1_b, h1_bf,
                                        1, 1, 0);
  h2_kernel<<<PBROWS, 256, 0, stream>>>(h1_bf, pb_w2, pb_b2, bias_tabT);
  // 4. flash attention -> regC (bf16, [b][n][h*64+d])
  flash_attn<<<dim3(SEQ / 64, NHEADS, BATCH), 128, 0, stream>>>(
      qb, kb, vbT, bias_tabT, null_bias, regC);
  // 5. out = LN(attn @ Wo)
  hipMemsetAsync((void*)regA, 0, 16777216, stream);
  gemm_bf16<<<dim3(8, 32, 2), 256, 0, stream>>>(regC, woT, regA, ROWS, 1024,
                                                1024);
  ln_kernel<<<ROWS, 256, 0, stream>>>(regA, nullptr, out_ln_g, out_ln_b, out, 0,
                                      0, 0);
}

// Round 11
// 416.407 us; speedup vs baseline: 1.4805x; 1.4805x over previous
//
#include <hip/hip_runtime.h>
#include <hip/hip_bf16.h>
#include <math.h>

#define DIMM   1024
#define NHEADS 16
#define DHEAD  64
#define BATCH  2
#define SEQ    2048
#define NKEYS  (SEQ + 1)      // 2049 (null + seq)
#define NKROWS 2112           // padded K rows
#define NKP    2112           // padded key count for V^T inner dim
#define PBROWS (2 * SEQ - 1)  // 4095
#define ROWS   (BATCH * SEQ)  // 4096

using bf16x8 = __attribute__((ext_vector_type(8))) short;
using bf16x4 = __attribute__((ext_vector_type(4))) short;
using f32x4  = __attribute__((ext_vector_type(4))) float;
typedef unsigned int u32;
typedef unsigned short u16;

__device__ __forceinline__ u16 f2bf(float f) {
  __hip_bfloat16 h = __float2bfloat16(f);
  return __builtin_bit_cast(u16, h);
}
__device__ __forceinline__ float bf2f(u16 u) {
  u32 x = ((u32)u) << 16;
  return __builtin_bit_cast(float, x);
}
__device__ __forceinline__ void gl_lds16(const void* g, void* l) {
  __builtin_amdgcn_global_load_lds(
      (const __attribute__((address_space(1))) u32*)g,
      (__attribute__((address_space(3))) u32*)l, 16, 0, 0);
}
// K=16 bf16 MFMA (PV step): D = A*B + C, in-place accumulate.
__device__ __forceinline__ f32x4 mfma16(bf16x4 a, bf16x4 b, f32x4 c) {
  asm("v_mfma_f32_16x16x16_bf16 %0, %1, %2, %0" : "+v"(c) : "v"(a), "v"(b));
  return c;
}

// ---------------------------------------------------------------------------
// LayerNorm over last dim (=1024).  obf16: output bf16.  posrow: input is
// w0[c]*(row-(SEQ-1)) + addb[c]  (fused dynamic-pos-bias first layer).
// ---------------------------------------------------------------------------
__global__ __launch_bounds__(256) void ln_kernel(
    const float* __restrict__ in, const float* __restrict__ addb,
    const float* __restrict__ g, const float* __restrict__ bvec,
    void* __restrict__ outv, int silu, int obf16, int posrow) {
  int row = blockIdx.x;
  int t = threadIdx.x;
  float4 x;
  if (posrow) {
    float p = (float)(row - (SEQ - 1));
    float4 wv = ((const float4*)in)[t];
    float4 a = ((const float4*)addb)[t];
    x.x = p * wv.x + a.x; x.y = p * wv.y + a.y;
    x.z = p * wv.z + a.z; x.w = p * wv.w + a.w;
  } else {
    x = ((const float4*)(in + (size_t)row * DIMM))[t];
    if (addb) {
      float4 a = ((const float4*)addb)[t];
      x.x += a.x; x.y += a.y; x.z += a.z; x.w += a.w;
    }
  }
  float s  = x.x + x.y + x.z + x.w;
  float ss = x.x * x.x + x.y * x.y + x.z * x.z + x.w * x.w;
#pragma unroll
  for (int off = 32; off > 0; off >>= 1) {
    s  += __shfl_down(s, off);
    ss += __shfl_down(ss, off);
  }
  __shared__ float rs[4], rss[4];
  int wv_ = t >> 6, lane = t & 63;
  if (lane == 0) { rs[wv_] = s; rss[wv_] = ss; }
  __syncthreads();
  float S  = rs[0] + rs[1] + rs[2] + rs[3];
  float SS = rss[0] + rss[1] + rss[2] + rss[3];
  float mu  = S * (1.0f / DIMM);
  float var = SS * (1.0f / DIMM) - mu * mu;
  float inv = rsqrtf(var + 1e-5f);
  float4 gv = ((const float4*)g)[t];
  float4 bv = ((const float4*)bvec)[t];
  float4 o;
  o.x = (x.x - mu) * inv * gv.x + bv.x;
  o.y = (x.y - mu) * inv * gv.y + bv.y;
  o.z = (x.z - mu) * inv * gv.z + bv.z;
  o.w = (x.w - mu) * inv * gv.w + bv.w;
  if (silu) {
    o.x = o.x / (1.f + expf(-o.x));
    o.y = o.y / (1.f + expf(-o.y));
    o.z = o.z / (1.f + expf(-o.z));
    o.w = o.w / (1.f + expf(-o.w));
  }
  if (obf16) {
    ushort4 ob;
    ob.x = f2bf(o.x); ob.y = f2bf(o.y); ob.z = f2bf(o.z); ob.w = f2bf(o.w);
    ((ushort4*)((u16*)outv + (size_t)row * DIMM))[t] = ob;
  } else {
    ((float4*)((float*)outv + (size_t)row * DIMM))[t] = o;
  }
}

// ---------------------------------------------------------------------------
// Weight convert+transpose: W f32 [K=1024][N] -> WT bf16 [rowOff+N][1024]
// ---------------------------------------------------------------------------
__global__ __launch_bounds__(256) void conv_wT(
    const float* __restrict__ W, u16* __restrict__ WT, int N, int rowOff) {
  __shared__ float tile[32][33];
  const int n0 = blockIdx.x * 32, k0 = blockIdx.y * 32;
  const int tc = threadIdx.x & 31, tr = threadIdx.x >> 5;  // tr 0..7
#pragma unroll
  for (int i = 0; i < 4; ++i)
    tile[tr + i * 8][tc] = W[(size_t)(k0 + tr + i * 8) * N + n0 + tc];
  __syncthreads();
#pragma unroll
  for (int i = 0; i < 4; ++i) {
    int r = tr + i * 8;
    WT[(size_t)(rowOff + n0 + r) * 1024 + k0 + tc] = f2bf(tile[tc][r]);
  }
}

// ---------------------------------------------------------------------------
// bf16 MFMA GEMM, 64x64 tile, BK=32, 4 waves (32x32 each).  4 blocks/CU at
// these shapes (vs 1/CU with 128^2 -- the m97 structure starves there).
// A bf16 [M][K], BT bf16 [N][K], C f32 [M][N].
// ---------------------------------------------------------------------------
__global__ __launch_bounds__(256) void gemm_bf16(
    const u16* __restrict__ A, const u16* __restrict__ BT,
    float* __restrict__ C, int M, int N, int K) {
  __shared__ u16 As[64 * 32];
  __shared__ u16 Bs[64 * 32];
  const int w = threadIdx.x >> 6, lane = threadIdx.x & 63;
  const int lo = lane & 15, hi = lane >> 4;
  const int wr = w >> 1, wc = w & 1;
  const int row0 = blockIdx.y * 64, col0 = blockIdx.x * 64;
  const int srow = lane >> 2;       // 0..15
  const int scol = (lane & 3) * 8;  // 0,8,16,24
  f32x4 acc[2][2];
#pragma unroll
  for (int m = 0; m < 2; ++m)
#pragma unroll
    for (int n = 0; n < 2; ++n) acc[m][n] = f32x4{0.f, 0.f, 0.f, 0.f};
  for (int k0 = 0; k0 < K; k0 += 32) {
    // wave w stages rows [w*16, w*16+16) of both tiles (wave-uniform base)
    gl_lds16(A + (size_t)(row0 + w * 16 + srow) * K + k0 + scol,
             &As[w * 16 * 32]);
    gl_lds16(BT + (size_t)(col0 + w * 16 + srow) * K + k0 + scol,
             &Bs[w * 16 * 32]);
    __syncthreads();
    bf16x8 af[2], bg[2];
#pragma unroll
    for (int m = 0; m < 2; ++m)
      af[m] = *(const bf16x8*)&As[(wr * 32 + m * 16 + lo) * 32 + hi * 8];
#pragma unroll
    for (int n = 0; n < 2; ++n)
      bg[n] = *(const bf16x8*)&Bs[(wc * 32 + n * 16 + lo) * 32 + hi * 8];
#pragma unroll
    for (int m = 0; m < 2; ++m)
#pragma unroll
      for (int n = 0; n < 2; ++n)
        acc[m][n] = __builtin_amdgcn_mfma_f32_16x16x32_bf16(af[m], bg[n],
                                                            acc[m][n], 0, 0, 0);
    __syncthreads();
  }
#pragma unroll
  for (int m = 0; m < 2; ++m)
#pragma unroll
    for (int r = 0; r < 4; ++r) {
      const int row = row0 + wr * 32 + m * 16 + hi * 4 + r;
      if (row < M) {
#pragma unroll
        for (int n = 0; n < 2; ++n)
          C[(size_t)row * N + col0 + wc * 32 + n * 16 + lo] = acc[m][n][r];
      }
    }
}

// ---------------------------------------------------------------------------
// q relayout from tmpQKV (stride 1152, cols 0..1023) -> bf16 [b][h][i][d] /8
// ---------------------------------------------------------------------------
__global__ __launch_bounds__(256) void relayout_q(
    const float* __restrict__ tmp, u16* __restrict__ qb) {
  size_t e = (size_t)blockIdx.x * 256 + threadIdx.x;
  int m = (int)(e >> 8), c4 = (int)(e & 255);
  int b = m >> 11, i = m & 2047;
  int h = c4 >> 4, d4 = c4 & 15;
  float4 v = ((const float4*)(tmp + (size_t)m * 1152))[c4];
  const float sc = 0.125f;
  ushort4 o;
  o.x = f2bf(v.x * sc); o.y = f2bf(v.y * sc);
  o.z = f2bf(v.z * sc); o.w = f2bf(v.w * sc);
  ((ushort4*)qb)[((size_t)(b * NHEADS + h) * SEQ + i) * 16 + d4] = o;
}

// kv relayout from tmpQKV cols 1024..1151 -> k bf16 [b][j][d], v^T [b][d][j]
__global__ __launch_bounds__(256) void relayout_kv(
    const float* __restrict__ tmp, u16* __restrict__ kb, u16* __restrict__ vbT) {
  size_t e = (size_t)blockIdx.x * 256 + threadIdx.x;
  int m = (int)(e >> 5), c4 = (int)(e & 31);
  int b = m >> 11, i = m & 2047;
  float4 v = ((const float4*)(tmp + (size_t)m * 1152 + 1024))[c4];
  if (c4 < 16) {
    ushort4 o;
    o.x = f2bf(v.x); o.y = f2bf(v.y); o.z = f2bf(v.z); o.w = f2bf(v.w);
    ((ushort4*)kb)[((size_t)b * NKROWS + (i + 1)) * 16 + c4] = o;
  } else {
    int d = (c4 - 16) * 4;
    size_t base = (size_t)b * DHEAD * NKP + (size_t)d * NKP + (i + 1);
    vbT[base]           = f2bf(v.x);
    vbT[base + NKP]     = f2bf(v.y);
    vbT[base + 2 * NKP] = f2bf(v.z);
    vbT[base + 3 * NKP] = f2bf(v.w);
  }
}

__global__ void fill_null(const float* __restrict__ null_kv,
                          u16* __restrict__ kb, u16* __restrict__ vbT) {
  int b = blockIdx.x, d = threadIdx.x;
  kb[(size_t)b * NKROWS * DHEAD + d] = f2bf(null_kv[d]);
  vbT[(size_t)b * DHEAD * NKP + (size_t)d * NKP] = f2bf(null_kv[DHEAD + d]);
}

// h2: bias_tabT[h][r] = h1[r][:] . w2[:][h] + b2[h]   (transposed table)
__global__ __launch_bounds__(256) void h2_kernel(
    const u16* __restrict__ h1, const float* __restrict__ w2,
    const float* __restrict__ b2, float* __restrict__ bias_tabT) {
  int r = blockIdx.x, t = threadIdx.x;
  int col = t & 15, seg = t >> 4;
  const u16* hr = h1 + (size_t)r * DIMM + seg * 64;
  const float* w2s = w2 + (size_t)seg * 64 * NHEADS + col;
  float acc = 0.f;
#pragma unroll
  for (int c = 0; c < 8; ++c) {
    bf16x8 hv = *(const bf16x8*)(hr + c * 8);
#pragma unroll
    for (int j = 0; j < 8; ++j)
      acc += bf2f((u16)hv[j]) * w2s[(size_t)(c * 8 + j) * NHEADS];
  }
  __shared__ float p[16][16];
  p[seg][col] = acc;
  __syncthreads();
  if (t < 16) {
    float s = 0.f;
#pragma unroll
    for (int q = 0; q < 16; q++) s += p[q][t];
    bias_tabT[(size_t)t * 4096 + r] = s + b2[t];
  }
}

// ---------------------------------------------------------------------------
// Flash attention (R7 config, best measured: 192us): 2 waves x 32 q-rows,
// KVBLK=64, swapped QK^T, K=16 register-direct PV (O^T), LDS-staged bias,
// K-frag prefetch, defer-max, direct bf16 out.
// ---------------------------------------------------------------------------
__global__ __launch_bounds__(128, 2) void flash_attn(
    const u16* __restrict__ qb, const u16* __restrict__ kb,
    const u16* __restrict__ vbT, const float* __restrict__ bias_tabT,
    const float* __restrict__ null_bias, u16* __restrict__ outb) {
  const int qt = gridDim.x - 1 - blockIdx.x;  // heavy blocks first
  const int h = blockIdx.y, b = blockIdx.z;
  const int tid = threadIdx.x;
  const int w = tid >> 6, lane = tid & 63;
  const int lo = lane & 15, hi = lane >> 4;
  const int q0 = qt * 64;
  const int rq0 = q0 + w * 32 + lo;  // f=0 q-row
  const int rq1 = rq0 + 16;          // f=1 q-row

  __shared__ float bias_lds[2][128];

  const size_t qbase = (size_t)(b * NHEADS + h) * SEQ;
  const u16* qrow0 = qb + (qbase + rq0) * DHEAD;
  const u16* qrow1 = qb + (qbase + rq1) * DHEAD;
  bf16x8 qa00 = *(const bf16x8*)(qrow0 + hi * 8);
  bf16x8 qa01 = *(const bf16x8*)(qrow0 + 32 + hi * 8);
  bf16x8 qa10 = *(const bf16x8*)(qrow1 + hi * 8);
  bf16x8 qa11 = *(const bf16x8*)(qrow1 + 32 + hi * 8);

  const u16* Kb = kb + (size_t)b * NKROWS * DHEAD;
  const u16* Vb = vbT + (size_t)b * DHEAD * NKP;
  const float* bt = bias_tabT + (size_t)h * 4096;
  const float nb = null_bias[h];

  f32x4 o[2][4];  // O^T[d = dc*16+hi*4+r][q = lane's row], per frag
#pragma unroll
  for (int f = 0; f < 2; ++f)
#pragma unroll
    for (int dc = 0; dc < 4; ++dc) o[f][dc] = f32x4{0.f, 0.f, 0.f, 0.f};
  float m_l[2] = {-3.0e38f, -3.0e38f};
  float l_l[2] = {0.f, 0.f};

  const int nkt = qt + 2;
  // prologue: K frags for tile 0
  bf16x8 kf0[4], kf1[4];
#pragma unroll
  for (int nf = 0; nf < 4; ++nf) {
    const u16* krow = Kb + (size_t)(nf * 16 + lo) * DHEAD;
    kf0[nf] = *(const bf16x8*)(krow + hi * 8);
    kf1[nf] = *(const bf16x8*)(krow + 32 + hi * 8);
  }

  for (int kt = 0; kt < nkt; ++kt) {
    const int j0 = kt * 64;
    // ---- stage bias window (127 floats, coalesced, double-buffered) ----
    {
      const int base = q0 - j0 - 63 + SEQ;
      if (tid < 127) bias_lds[kt & 1][tid] = bt[base + tid];
    }
    __syncthreads();
    // ---- S^T = K @ Q (both q-frags share K frags) ----
    f32x4 s[2][4];
    __builtin_amdgcn_s_setprio(1);
#pragma unroll
    for (int nf = 0; nf < 4; ++nf) {
      f32x4 a0 = f32x4{0.f, 0.f, 0.f, 0.f};
      f32x4 a1 = f32x4{0.f, 0.f, 0.f, 0.f};
      a0 = __builtin_amdgcn_mfma_f32_16x16x32_bf16(kf0[nf], qa00, a0, 0, 0, 0);
      a0 = __builtin_amdgcn_mfma_f32_16x16x32_bf16(kf1[nf], qa01, a0, 0, 0, 0);
      a1 = __builtin_amdgcn_mfma_f32_16x16x32_bf16(kf0[nf], qa10, a1, 0, 0, 0);
      a1 = __builtin_amdgcn_mfma_f32_16x16x32_bf16(kf1[nf], qa11, a1, 0, 0, 0);
      s[0][nf] = a0;
      s[1][nf] = a1;
    }
    __builtin_amdgcn_s_setprio(0);
    // ---- prefetch K frags for tile t+1 (hidden under softmax+PV) ----
    {
      const int jn = (kt + 1 < nkt ? kt + 1 : kt) * 64;
#pragma unroll
      for (int nf = 0; nf < 4; ++nf) {
        const u16* krow = Kb + (size_t)(jn + nf * 16 + lo) * DHEAD;
        kf0[nf] = *(const bf16x8*)(krow + hi * 8);
        kf1[nf] = *(const bf16x8*)(krow + 32 + hi * 8);
      }
    }
    // ---- V^T frags (A of PV, K=16): row=lo->d, k=hi*4+j -> key ----
    bf16x4 vf[4][4];
#pragma unroll
    for (int dc = 0; dc < 4; ++dc) {
      const u16* vrow = Vb + (size_t)(dc * 16 + lo) * NKP + j0 + hi * 4;
#pragma unroll
      for (int kc = 0; kc < 4; ++kc)
        vf[dc][kc] = *(const bf16x4*)(vrow + kc * 16);
    }
    // ---- bias (from LDS) + causal mask + row max ----
    const float* bl = bias_lds[kt & 1];
    float tm[2] = {-3.0e38f, -3.0e38f};
#pragma unroll
    for (int f = 0; f < 2; ++f) {
      const int rq = (f == 0) ? rq0 : rq1;
      const int qrel = w * 32 + f * 16 + lo + 63;
#pragma unroll
      for (int nf = 0; nf < 4; ++nf)
#pragma unroll
        for (int r = 0; r < 4; ++r) {
          const int krel = nf * 16 + hi * 4 + r;
          const int key = j0 + krel;
          float bias = bl[qrel - krel];
          if (key == 0) bias = nb;
          float v = (key <= rq + 1) ? (s[f][nf][r] + bias) : -3.0e38f;
          s[f][nf][r] = v;
          tm[f] = fmaxf(tm[f], v);
        }
      tm[f] = fmaxf(tm[f], __shfl_xor(tm[f], 16));
      tm[f] = fmaxf(tm[f], __shfl_xor(tm[f], 32));
    }
    // ---- defer-max rescale (lane-local o) ----
    if (__any((tm[0] > m_l[0] + 8.0f) || (tm[1] > m_l[1] + 8.0f))) {
#pragma unroll
      for (int f = 0; f < 2; ++f) {
        float mn = fmaxf(m_l[f], tm[f]);
        float sco = __expf(m_l[f] - mn);
        m_l[f] = mn;
        l_l[f] *= sco;
#pragma unroll
        for (int dc = 0; dc < 4; ++dc)
#pragma unroll
          for (int r = 0; r < 4; ++r) o[f][dc][r] *= sco;
      }
    }
    // ---- exp + per-lane partial sum + pack P as K=16 B-frags ----
    bf16x4 pbf[2][4];
#pragma unroll
    for (int f = 0; f < 2; ++f)
#pragma unroll
      for (int nf = 0; nf < 4; ++nf) {
        float p0 = __expf(s[f][nf][0] - m_l[f]);
        float p1 = __expf(s[f][nf][1] - m_l[f]);
        float p2 = __expf(s[f][nf][2] - m_l[f]);
        float p3 = __expf(s[f][nf][3] - m_l[f]);
        l_l[f] += (p0 + p1) + (p2 + p3);
        pbf[f][nf][0] = (short)f2bf(p0);
        pbf[f][nf][1] = (short)f2bf(p1);
        pbf[f][nf][2] = (short)f2bf(p2);
        pbf[f][nf][3] = (short)f2bf(p3);
      }
    // ---- O^T += V^T @ P^T (32x K=16 MFMA, register-direct) ----
    __builtin_amdgcn_s_setprio(1);
#pragma unroll
    for (int f = 0; f < 2; ++f)
#pragma unroll
      for (int dc = 0; dc < 4; ++dc)
#pragma unroll
        for (int kc = 0; kc < 4; ++kc)
          o[f][dc] = mfma16(vf[dc][kc], pbf[f][kc], o[f][dc]);
    __builtin_amdgcn_s_setprio(0);
  }
  asm volatile("s_nop 7\ns_nop 7" :::);  // asm-MFMA -> VALU hazard guard
  // ---- final l reduce + lane-local normalize + stores ----
#pragma unroll
  for (int f = 0; f < 2; ++f) {
    float lf = l_l[f];
    lf += __shfl_xor(lf, 16);
    lf += __shfl_xor(lf, 32);
    float linv = 1.0f / lf;
    const int rq = (f == 0) ? rq0 : rq1;
    u16* orow = outb + (size_t)(b * SEQ + rq) * DIMM + h * DHEAD + hi * 4;
#pragma unroll
    for (int dc = 0; dc < 4; ++dc) {
      ushort4 st;
      st.x = f2bf(o[f][dc][0] * linv);
      st.y = f2bf(o[f][dc][1] * linv);
      st.z = f2bf(o[f][dc][2] * linv);
      st.w = f2bf(o[f][dc][3] * linv);
      *(ushort4*)(orow + dc * 16) = st;
    }
  }
}

// ---------------------------------------------------------------------------
extern "C" void kernel_launch(void* const* d_in, const int* in_sizes, int n_in,
                              void* d_out, int out_size, void* d_ws,
                              size_t ws_size, hipStream_t stream) {
  const float* x         = (const float*)d_in[0];
  const float* ln_g      = (const float*)d_in[1];
  const float* ln_b      = (const float*)d_in[2];
  const float* Wq        = (const float*)d_in[3];
  const float* Wkv       = (const float*)d_in[4];
  const float* null_kv   = (const float*)d_in[5];
  const float* null_bias = (const float*)d_in[6];
  const float* pb_w0     = (const float*)d_in[7];
  const float* pb_b0     = (const float*)d_in[8];
  const float* pb_ln0_g  = (const float*)d_in[9];
  const float* pb_ln0_b  = (const float*)d_in[10];
  const float* pb_w1     = (const float*)d_in[11];
  const float* pb_b1     = (const float*)d_in[12];
  const float* pb_ln1_g  = (const float*)d_in[13];
  const float* pb_ln1_b  = (const float*)d_in[14];
  const float* pb_w2     = (const float*)d_in[15];
  const float* pb_b2     = (const float*)d_in[16];
  const float* Wo        = (const float*)d_in[17];
  const float* out_ln_g  = (const float*)d_in[18];
  const float* out_ln_b  = (const float*)d_in[19];
  float* out = (float*)d_out;

  char* ws = (char*)d_ws;
  float* regA      = (float*)(ws);                      // f32 4096x1152
  u16*   h1_bf     = (u16*)(ws + 18874368);             // bf16 4095x1024
  u16*   regC      = (u16*)(ws + 35651584);             // bf16 4096x1024
  u16*   qb        = (u16*)(ws + 44040192);             // bf16 q
  u16*   kb        = (u16*)(ws + 52428800);             // bf16 K padded
  u16*   vbT       = (u16*)(ws + 52969472);             // bf16 V^T padded
  u16*   wqkvT     = (u16*)(ws + 53510144);             // 1152x1024 bf16
  u16*   w1T       = (u16*)(ws + 55869440);             // 1024x1024 bf16
  u16*   woT       = (u16*)(ws + 57966592);             // 1024x1024 bf16
  float* bias_tabT = (float*)(ws + 60063744);           // f32 [16][4096]

  hipMemsetAsync((void*)kb, 0, 1081344, stream);

  conv_wT<<<dim3(32, 32), 256, 0, stream>>>(Wq, wqkvT, 1024, 0);
  conv_wT<<<dim3(4, 32), 256, 0, stream>>>(Wkv, wqkvT, 128, 1024);
  conv_wT<<<dim3(32, 32), 256, 0, stream>>>(pb_w1, w1T, 1024, 0);
  conv_wT<<<dim3(32, 32), 256, 0, stream>>>(Wo, woT, 1024, 0);

  // 1. xn = LN(x) -> bf16
  ln_kernel<<<ROWS, 256, 0, stream>>>(x, nullptr, ln_g, ln_b, regC, 0, 1, 0);
  // 2. fused q|kv GEMM (64^2 tile -> 1152 blocks, ~4/CU)
  gemm_bf16<<<dim3(1152 / 64, ROWS / 64), 256, 0, stream>>>(regC, wqkvT, regA,
                                                            ROWS, 1152, 1024);
  relayout_q<<<4096, 256, 0, stream>>>(regA, qb);
  relayout_kv<<<512, 256, 0, stream>>>(regA, kb, vbT);
  fill_null<<<2, 64, 0, stream>>>(null_kv, kb, vbT);
  // 3. pos-bias MLP (first layer fused into LN)
  ln_kernel<<<PBROWS, 256, 0, stream>>>(pb_w0, pb_b0, pb_ln0_g, pb_ln0_b, regC,
                                        1, 1, 1);
  gemm_bf16<<<dim3(DIMM / 64, (PBROWS + 63) / 64), 256, 0, stream>>>(
      regC, w1T, regA, PBROWS, 1024, 1024);
  ln_kernel<<<PBROWS, 256, 0, stream>>>(regA, pb_b1, pb_ln1_g, pb_ln1_b, h1_bf,
                                        1, 1, 0);
  h2_kernel<<<PBROWS, 256, 0, stream>>>(h1_bf, pb_w2, pb_b2, bias_tabT);
  // 4. flash attention -> regC (bf16, [b][n][h*64+d])
  flash_attn<<<dim3(SEQ / 64, NHEADS, BATCH), 128, 0, stream>>>(
      qb, kb, vbT, bias_tabT, null_bias, regC);
  // 5. out = LN(attn @ Wo)
  gemm_bf16<<<dim3(DIMM / 64, ROWS / 64), 256, 0, stream>>>(regC, woT, regA,
                                                            ROWS, 1024, 1024);
  ln_kernel<<<ROWS, 256, 0, stream>>>(regA, nullptr, out_ln_g, out_ln_b, out, 0,
                                      0, 0);
}